// Round 10
// baseline (285.906 us; speedup 1.0000x reference)
//
#include <hip/hip_runtime.h>
#include <math.h>

// Problem constants
#define N_CLASS 64
#define N_SUPPORT 5
#define N_QUERY 64
#define D_IN 1024
#define C_CH 128
#define WIN 5
#define D_FEAT 3200            // C*WIN*WIN
#define NS 320                 // N_CLASS*N_SUPPORT
#define NQ 4096                // N_CLASS*N_QUERY
#define M_ROWS 4416            // NS+NQ
#define M_PAD 4480             // 35 * 128

#define ZP_SLICE  (N_CLASS * D_FEAT)          // 204800
#define GT_SLICE  (128 * D_FEAT)              // 409600
#define CR_SLICE  (NQ * 128)                  // 524288
#define NKS       10                          // split-K slices
#define LOSS_BLKS (NQ / 4)                    // 1024

// prep kernel block-range partition (x + W_share only; Wf fused into gemm_fp8)
#define PREP_X   4480                          // x->fp8 blocks
#define PREP_WS  3200                          // 100 x 32 (32x32 tiles)
#define PREP_WF  10000                         // Wf conversion blocks (in gemm_fp8)

#define WS_SCALE    64.0f                      // W_share fp8 pre-scale (avoids denormals)
#define WS_INVSCALE 0.015625f

typedef __bf16 bf16x8 __attribute__((ext_vector_type(8)));
typedef __bf16 bf16x4 __attribute__((ext_vector_type(4)));
typedef float floatx4 __attribute__((ext_vector_type(4)));
typedef __attribute__((address_space(1))) const void* gptr_t;
typedef __attribute__((address_space(3))) void* lptr_t;

__device__ __forceinline__ float waveReduceSum(float v) {
    for (int off = 32; off > 0; off >>= 1) v += __shfl_xor(v, off, 64);
    return v;
}

// ------ prep: x->fp8 | W_share^T->fp8(x64); rows with (row>>3)&1 get their 8B
// ------ halves swapped inside each 16B unit (conflict-free fp8 LDS reads later)
__global__ __launch_bounds__(256) void prep_kernel(const float* __restrict__ xs,
                                                   const float* __restrict__ xq,
                                                   const float* __restrict__ W_share,
                                                   unsigned char* __restrict__ Xf8,
                                                   unsigned char* __restrict__ Wsf8)
{
    __shared__ float tile[32][33];
    const int b = blockIdx.x;
    const int t = threadIdx.x;

    if (b < PREP_X) {
        // x (xs|xq|zero-pad) -> fp8 e4m3 [M_PAD][1024], 4 elems per thread
        const int e = (b * 256 + t) * 4;
        const int row = e >> 10;
        const int col = e & 1023;
        float4 v = make_float4(0.f, 0.f, 0.f, 0.f);
        if (row < NS)          v = *(const float4*)(xs + (size_t)row * D_IN + col);
        else if (row < M_ROWS) v = *(const float4*)(xq + (size_t)(row - NS) * D_IN + col);
        int p = __builtin_amdgcn_cvt_pk_fp8_f32(v.x, v.y, 0, false);
        p     = __builtin_amdgcn_cvt_pk_fp8_f32(v.z, v.w, p, true);
        const int ocol = col ^ (((row >> 3) & 1) << 3);     // half-swap
        *(int*)(Xf8 + (size_t)row * D_IN + ocol) = p;
        return;
    }
    // W_share [1024][3200] -> Wsf8 [3200][1024] fp8, scaled x64, half-swapped
    const int tx = t & 31;
    const int ty = t >> 5;
    const int tb = b - PREP_X;
    const int n0 = (tb % 100) * 32;
    const int k0 = (tb / 100) * 32;
#pragma unroll
    for (int i = ty; i < 32; i += 8)
        tile[i][tx] = W_share[(size_t)(k0 + i) * D_FEAT + n0 + tx];
    __syncthreads();
#pragma unroll
    for (int i = ty; i < 32; i += 8) {
        const int p = __builtin_amdgcn_cvt_pk_fp8_f32(tile[tx][i] * WS_SCALE, 0.f,
                                                      0, false);
        const int n = n0 + i;
        const int k = (k0 + tx) ^ (((n >> 3) & 1) << 3);    // half-swap
        Wsf8[(size_t)n * D_IN + k] = (unsigned char)(p & 0xff);
    }
}

// -------- fp8 MFMA GEMM (gemm1) + fused W_fine dual-layout conversion -------------
// Blocks [0, nbx*nby): out_bf16 = relu(A @ Bt^T * 1/64 + bias); 128x128 tile,
// BK=128, LDS rows 128 B. Store: 16B slot = c16 ^ (row&7). Read: unit =
// (qq>>1)^(r16&7), half = (qq&1)^((r16>>3)&1) [data pre-half-swapped in prep] ->
// each 16-lane phase covers all 32 banks exactly once: conflict-free.
// Blocks [nbx*nby, +PREP_WF): W_fine f32 -> Wfb natural + WfTb transposed (bf16),
// overlapped with the latency-bound GEMM in the same dispatch (consumers launch
// 3 kernels later).
__global__ __launch_bounds__(256) void gemm_fp8(const unsigned char* __restrict__ A,
                                                const unsigned char* __restrict__ Bt,
                                                const float* __restrict__ bias,
                                                __bf16* __restrict__ out_bf,
                                                const float* __restrict__ W_fine,
                                                __bf16* __restrict__ Wfb,
                                                __bf16* __restrict__ WfTb,
                                                int N, int strideK, int kIters,
                                                int Mout, int nbx, int nby)
{
    __shared__ __align__(16) char smem[32768];   // A tile @0 (16 KB) | B tile @16384
    const int nbxy = nbx * nby;

    if (blockIdx.x >= nbxy) {
        // ---- fused W_fine dual conversion block ----
        float (*tile)[33] = (float(*)[33])smem;
        const int tb = blockIdx.x - nbxy;
        const int tx = threadIdx.x & 31;
        const int ty = threadIdx.x >> 5;
        const int n0 = (tb % 100) * 32;
        const int k0 = (tb / 100) * 32;
#pragma unroll
        for (int i = ty; i < 32; i += 8) {
            const float v = W_fine[(size_t)(k0 + i) * D_FEAT + n0 + tx];
            Wfb[(size_t)(k0 + i) * D_FEAT + n0 + tx] = (__bf16)v;
            tile[i][tx] = v;
        }
        __syncthreads();
#pragma unroll
        for (int i = ty; i < 32; i += 8)
            WfTb[(size_t)(n0 + i) * D_FEAT + k0 + tx] = (__bf16)tile[tx][i];
        return;
    }

    int bx, by;
    {
        const int b  = blockIdx.x;
        const int fg = nbx >> 3;
        const int full = fg * 8 * nby;
        if (b < full) {
            const int g = b / (8 * nby);
            const int r = b - g * 8 * nby;
            bx = g * 8 + (r & 7);
            by = r >> 3;
        } else {
            const int rem = nbx - fg * 8;
            const int r = b - full;
            bx = fg * 8 + r % rem;
            by = r / rem;
        }
    }

    const int t    = threadIdx.x;
    const int lane = t & 63;
    const int w    = t >> 6;
    const int wm   = w >> 1;
    const int wn   = w & 1;
    const int bm   = by * 128;
    const int bn   = bx * 128;

    const int q    = lane >> 4;       // k-group within 32-k subtile
    const int r16  = lane & 15;
    const int b7   = r16 & 7;
    const int hs   = (r16 >> 3) & 1;  // half-select (matches prep's pre-swap)

    // staging line geometry (line i: rows i*32 + (t>>3), slot t&7)
    const int smRow  = t >> 3;                        // 0..31 (+ i*32)
    const int sgk16  = ((t & 7) ^ ((t >> 3) & 7)) * 16;  // global chunk byte offset

    floatx4 acc[4][4] = {};

    for (int ki = 0; ki < kIters; ++ki) {
        const int k0 = ki * 128;
        __syncthreads();
#pragma unroll
        for (int i = 0; i < 4; ++i) {
            const unsigned char* ga = A  + (size_t)(bm + i * 32 + smRow) * strideK
                                         + k0 + sgk16;
            const unsigned char* gb = Bt + (size_t)(bn + i * 32 + smRow) * strideK
                                         + k0 + sgk16;
            char* la = smem +         i * 4096 + t * 16;
            char* lb = smem + 16384 + i * 4096 + t * 16;
            __builtin_amdgcn_global_load_lds((gptr_t)ga, (lptr_t)la, 16, 0, 0);
            __builtin_amdgcn_global_load_lds((gptr_t)gb, (lptr_t)lb, 16, 0, 0);
        }
        __syncthreads();

#pragma unroll
        for (int s32 = 0; s32 < 4; ++s32) {
            const int qq = s32 * 4 + q;               // k-group 0..15
            const int colOff = (((qq >> 1) ^ b7) * 16) + (((qq & 1) ^ hs) * 8);
            long av[4], bv[4];
#pragma unroll
            for (int mi = 0; mi < 4; ++mi)
                av[mi] = *(const long*)(smem
                            + (wm * 64 + mi * 16 + r16) * 128 + colOff);
#pragma unroll
            for (int ni = 0; ni < 4; ++ni)
                bv[ni] = *(const long*)(smem + 16384
                            + (wn * 64 + ni * 16 + r16) * 128 + colOff);
#pragma unroll
            for (int mi = 0; mi < 4; ++mi)
#pragma unroll
                for (int ni = 0; ni < 4; ++ni)
                    acc[mi][ni] = __builtin_amdgcn_mfma_f32_16x16x32_fp8_fp8(
                        av[mi], bv[ni], acc[mi][ni], 0, 0, 0);
        }
    }

    // epilogue: C/D layout col=lane&15, row=(lane>>4)*4+reg; descale 1/64
#pragma unroll
    for (int ni = 0; ni < 4; ++ni) {
        const int col = bn + wn * 64 + ni * 16 + r16;
        const float bcol = bias[col];
#pragma unroll
        for (int mi = 0; mi < 4; ++mi) {
#pragma unroll
            for (int reg = 0; reg < 4; ++reg) {
                const int row = bm + wm * 64 + mi * 16 + q * 4 + reg;
                if (row < Mout) {
                    float v = acc[mi][ni][reg] * WS_INVSCALE + bcol;
                    v = fmaxf(v, 0.f);
                    out_bf[(size_t)row * N + col] = (__bf16)v;
                }
            }
        }
    }
}

// ---------------- bf16 MFMA GEMM: split-K partials or full ----------------
__global__ __launch_bounds__(256) void gemm_bf16(const __bf16* __restrict__ A,
                                                 const __bf16* __restrict__ Bt,
                                                 const float* __restrict__ bias,
                                                 __bf16* __restrict__ out_bf,
                                                 float* __restrict__ out_f32,
                                                 int N, int strideK, int kIters,
                                                 int Mout, int relu, int sliceStride,
                                                 int nbx, int nby)
{
    __shared__ __align__(16) char smem[32768];   // sA: s0@0 s1@8192 | sB: @16384,@24576

    int bx, by, ks;
    {
        const int nbxy = nbx * nby;
        ks = blockIdx.x / nbxy;
        const int b = blockIdx.x - ks * nbxy;
        const int fg = nbx >> 3;
        const int full = fg * 8 * nby;
        if (b < full) {
            const int g = b / (8 * nby);
            const int r = b - g * 8 * nby;
            bx = g * 8 + (r & 7);
            by = r >> 3;
        } else {
            const int rem = nbx - fg * 8;
            const int r = b - full;
            bx = fg * 8 + r % rem;
            by = r / rem;
        }
    }

    const int t    = threadIdx.x;
    const int lane = t & 63;
    const int w    = t >> 6;
    const int wm   = w >> 1;
    const int wn   = w & 1;
    const int bm   = by * 128;
    const int bn   = bx * 128;

    const int q    = lane >> 4;
    const int r16  = lane & 15;
    const int sw   = (r16 >> 1) & 3;
    const int cA   = (q ^ sw) * 8;

    const int srow   = w * 16 + (lane >> 2);
    const int sglob8 = (((lane & 3) ^ ((lane >> 3) & 3))) * 8;

    const int kBase = ks * kIters * 64;
    floatx4 acc[4][4] = {};

    for (int ki = 0; ki < kIters; ++ki) {
        const int k0 = kBase + ki * 64;
        __syncthreads();
#pragma unroll
        for (int s = 0; s < 2; ++s) {
#pragma unroll
            for (int j = 0; j < 2; ++j) {
                const __bf16* ga = A  + (size_t)(bm + j * 64 + srow) * strideK
                                      + k0 + s * 32 + sglob8;
                const __bf16* gb = Bt + (size_t)(bn + j * 64 + srow) * strideK
                                      + k0 + s * 32 + sglob8;
                char* la = smem +         s * 8192 + (j * 256 + w * 64) * 16;
                char* lb = smem + 16384 + s * 8192 + (j * 256 + w * 64) * 16;
                __builtin_amdgcn_global_load_lds((gptr_t)ga, (lptr_t)la, 16, 0, 0);
                __builtin_amdgcn_global_load_lds((gptr_t)gb, (lptr_t)lb, 16, 0, 0);
            }
        }
        __syncthreads();

#pragma unroll
        for (int s = 0; s < 2; ++s) {
            const __bf16* sAe = (const __bf16*)(smem +         s * 8192);
            const __bf16* sBe = (const __bf16*)(smem + 16384 + s * 8192);
            bf16x8 av[4], bv[4];
#pragma unroll
            for (int mi = 0; mi < 4; ++mi)
                av[mi] = *(const bf16x8*)(sAe + ((wm * 64 + mi * 16 + r16) * 32 + cA));
#pragma unroll
            for (int ni = 0; ni < 4; ++ni)
                bv[ni] = *(const bf16x8*)(sBe + ((wn * 64 + ni * 16 + r16) * 32 + cA));
#pragma unroll
            for (int mi = 0; mi < 4; ++mi)
#pragma unroll
                for (int ni = 0; ni < 4; ++ni)
                    acc[mi][ni] = __builtin_amdgcn_mfma_f32_16x16x32_bf16(
                        av[mi], bv[ni], acc[mi][ni], 0, 0, 0);
        }
    }

#pragma unroll
    for (int ni = 0; ni < 4; ++ni) {
        const int col = bn + wn * 64 + ni * 16 + r16;
        const float bcol = sliceStride ? 0.f : bias[col];
#pragma unroll
        for (int mi = 0; mi < 4; ++mi) {
#pragma unroll
            for (int reg = 0; reg < 4; ++reg) {
                const int row = bm + wm * 64 + mi * 16 + q * 4 + reg;
                if (row < Mout) {
                    if (sliceStride) {
                        out_f32[(size_t)ks * sliceStride + (size_t)row * N + col] =
                            acc[mi][ni][reg];
                    } else {
                        float v = acc[mi][ni][reg] + bcol;
                        if (relu) v = fmaxf(v, 0.f);
                        if (out_f32) out_f32[(size_t)row * N + col] = v;
                        else         out_bf [(size_t)row * N + col] = (__bf16)v;
                    }
                }
            }
        }
    }
}

// ------- u[p][k] = support mean (bf16, pad rows 0) + per-class channel pools --------
__global__ __launch_bounds__(256) void ut_kernel(const __bf16* __restrict__ z_share,
                                                 __bf16* __restrict__ u,
                                                 float* __restrict__ upool)
{
    __shared__ float srow_[D_FEAT];
    const int p = blockIdx.x;        // 0..127
    const int t = threadIdx.x;
    if (p >= N_CLASS) {
        for (int k = t; k < D_FEAT; k += 256) u[(size_t)p * D_FEAT + k] = (__bf16)0.f;
        return;
    }
    const __bf16* base = z_share + (size_t)(p * N_SUPPORT) * D_FEAT;
    for (int k = t; k < D_FEAT; k += 256) {
        float s = 0.f;
#pragma unroll
        for (int ss = 0; ss < N_SUPPORT; ++ss) s += (float)base[(size_t)ss * D_FEAT + k];
        s *= (1.0f / N_SUPPORT);
        u[(size_t)p * D_FEAT + k] = (__bf16)s;
        srow_[k] = s;
    }
    __syncthreads();
    if (t < C_CH) {
        float pool = 0.f;
#pragma unroll
        for (int win = 0; win < 25; ++win) pool += srow_[t * 25 + win];
        upool[(size_t)p * C_CH + t] = pool;
    }
}

// ------------- att: pooled mean (from upool) -> matvec -> softmax -> w[3200] --------
__global__ __launch_bounds__(128) void att2_kernel(const float* __restrict__ upool,
                                                   const float* __restrict__ W_att,
                                                   const float* __restrict__ b_att,
                                                   float* __restrict__ wvec)
{
    __shared__ float s_pm[C_CH];
    __shared__ float s_att[C_CH];
    __shared__ float s_diag[C_CH];
    const int c = threadIdx.x;
    float a = 0.f;
    for (int p = 0; p < N_CLASS; ++p) a += upool[(size_t)p * C_CH + c];
    s_pm[c] = a * (1.0f / (N_CLASS * 25));
    __syncthreads();
    float acc = b_att[c];
    for (int k = 0; k < C_CH; ++k) acc += s_pm[k] * W_att[k * C_CH + c];
    s_att[c] = acc;
    __syncthreads();
    float m = -INFINITY;
    for (int k = 0; k < C_CH; ++k) m = fmaxf(m, s_att[k]);
    float s = 0.f;
    for (int k = 0; k < C_CH; ++k) s += expf(s_att[k] - m);
    s_diag[c] = expf(acc - m) / s * (float)C_CH;
    __syncthreads();
    for (int j = c; j < D_FEAT; j += C_CH) wvec[j] = s_diag[j / 25];
}

// ---------------- y = w*(sum zp_part + bf) bf16 [128 pad][3200]; p2; c --------------
__global__ __launch_bounds__(256) void y_kernel(const float* __restrict__ zp_part,
                                                const float* __restrict__ wv,
                                                const float* __restrict__ bf,
                                                __bf16* __restrict__ y,
                                                float* __restrict__ p2,
                                                float* __restrict__ cvec)
{
    __shared__ float s_red2[8];
    const int p = blockIdx.x;        // 0..127
    const int t = threadIdx.x;
    if (p >= N_CLASS) {
        for (int j = t; j < D_FEAT; j += 256) y[(size_t)p * D_FEAT + j] = (__bf16)0.f;
        return;
    }
    float s2 = 0.f, sc = 0.f;
    for (int j = t; j < D_FEAT; j += 256) {
        float zpf = bf[j];
#pragma unroll
        for (int ss = 0; ss < NKS; ++ss)
            zpf += zp_part[(size_t)ss * ZP_SLICE + (size_t)p * D_FEAT + j];
        const float wj = wv[j];
        y[(size_t)p * D_FEAT + j] = (__bf16)(wj * zpf);
        s2 += wj * zpf * zpf;
        sc += bf[j] * wj * zpf;
    }
    s2 = waveReduceSum(s2);
    sc = waveReduceSum(sc);
    const int lane = t & 63, wid = t >> 6;
    if (lane == 0) { s_red2[wid] = s2; s_red2[4 + wid] = sc; }
    __syncthreads();
    if (t == 0) {
        p2[p]   = s_red2[0] + s_red2[1] + s_red2[2] + s_red2[3];
        cvec[p] = s_red2[4] + s_red2[5] + s_red2[6] + s_red2[7];
    }
}

// ---------------- Gt[p][k] bf16 = sum of NKS fp32 slices [128][3200] ----------------
__global__ __launch_bounds__(256) void gtsum_kernel(const float* __restrict__ gp,
                                                    __bf16* __restrict__ Gt)
{
    const int i4 = blockIdx.x * 256 + threadIdx.x;     // over 409600/4
    if (i4 >= GT_SLICE / 4) return;
    float4 s = make_float4(0.f, 0.f, 0.f, 0.f);
#pragma unroll
    for (int ss = 0; ss < NKS; ++ss) {
        const float4 v = *(const float4*)(gp + (size_t)ss * GT_SLICE + i4 * 4);
        s.x += v.x; s.y += v.y; s.z += v.z; s.w += v.w;
    }
    bf16x4 o = { (__bf16)s.x, (__bf16)s.y, (__bf16)s.z, (__bf16)s.w };
    *(bf16x4*)(Gt + (size_t)i4 * 4) = o;
}

// ---------------- softmax/loss: one wave per query, block partials (no atomics) -----
__global__ __launch_bounds__(256) void loss_kernel(const float* __restrict__ cross_part,
                                                   const float* __restrict__ p2,
                                                   const float* __restrict__ cvec,
                                                   float* __restrict__ lpart)
{
    __shared__ float s_l[4], s_a[4];
    const int t = threadIdx.x;
    const int lane = t & 63, wid = t >> 6;
    const int i = blockIdx.x * 4 + wid;       // query 0..4095
    float cr = 0.f;
#pragma unroll
    for (int ss = 0; ss < NKS; ++ss)
        cr += cross_part[(size_t)ss * CR_SLICE + (size_t)i * 128 + lane];
    const float neg = 2.0f * (cr + cvec[lane]) - p2[lane];   // -(dist) + const/row
    float m = neg;
    for (int off = 32; off > 0; off >>= 1) m = fmaxf(m, __shfl_xor(m, off, 64));
    float e = expf(neg - m);
    float ssum = e;
    for (int off = 32; off > 0; off >>= 1) ssum += __shfl_xor(ssum, off, 64);
    const float lse = m + logf(ssum);
    const int tcls = i >> 6;
    const float negt = __shfl(neg, tcls, 64);
    float v = -neg; int bi = lane;            // argmin dist == argmax neg, first on tie
    for (int off = 32; off > 0; off >>= 1) {
        const float ov = __shfl_xor(v, off, 64);
        const int   oi = __shfl_xor(bi, off, 64);
        if (ov < v || (ov == v && oi < bi)) { v = ov; bi = oi; }
    }
    if (lane == 0) { s_l[wid] = lse - negt; s_a[wid] = (bi == tcls) ? 1.0f : 0.0f; }
    __syncthreads();
    if (t == 0) {
        lpart[blockIdx.x]             = s_l[0] + s_l[1] + s_l[2] + s_l[3];
        lpart[LOSS_BLKS + blockIdx.x] = s_a[0] + s_a[1] + s_a[2] + s_a[3];
    }
}

__global__ __launch_bounds__(256) void writeout_kernel(const float* __restrict__ lpart,
                                                       float* __restrict__ out)
{
    __shared__ float s_red2[8];
    const int t = threadIdx.x;
    float l = 0.f, a = 0.f;
    for (int k = t; k < LOSS_BLKS; k += 256) {
        l += lpart[k];
        a += lpart[LOSS_BLKS + k];
    }
    l = waveReduceSum(l);
    a = waveReduceSum(a);
    const int lane = t & 63, wid = t >> 6;
    if (lane == 0) { s_red2[wid] = l; s_red2[4 + wid] = a; }
    __syncthreads();
    if (t == 0) {
        out[0] = (s_red2[0] + s_red2[1] + s_red2[2] + s_red2[3]) * (1.0f / NQ);
        out[1] = (s_red2[4] + s_red2[5] + s_red2[6] + s_red2[7]) * (1.0f / NQ);
    }
}

extern "C" void kernel_launch(void* const* d_in, const int* in_sizes, int n_in,
                              void* d_out, int out_size, void* d_ws, size_t ws_size,
                              hipStream_t stream)
{
    const float* xs      = (const float*)d_in[0];
    const float* xq      = (const float*)d_in[1];
    const float* W_share = (const float*)d_in[2];
    const float* b_share = (const float*)d_in[3];
    const float* W_att   = (const float*)d_in[4];
    const float* b_att   = (const float*)d_in[5];
    const float* W_fine  = (const float*)d_in[6];
    const float* b_fine  = (const float*)d_in[7];
    float* out = (float*)d_out;

    // workspace layout (bytes); arena holds upool -> zp_part -> gt_part -> cr_part
    char* ws = (char*)d_ws;
    unsigned char* Xf8  = (unsigned char*)(ws);        //   4,587,520 [M_PAD][1024] fp8
    unsigned char* Wsf8 = (unsigned char*)(ws + 4587520); // 3,276,800 [3200][1024] fp8
    __bf16* Zsb     = (__bf16*)(ws +   7864320);       //  28,672,000
    __bf16* Wfb     = (__bf16*)(ws +  36536320);       //  20,480,000 natural [k][j]
    __bf16* WfTb    = (__bf16*)(ws +  57016320);       //  20,480,000 transposed [j][k]
    float*  arena   = (float*) (ws +  77496320);       //  20,971,520
    float*  upool   = arena;                           //  64*128*4 (dead before zp)
    float*  zp_part = arena;                           //  10*204800*4 =  8,192,000
    float*  gt_part = arena;                           //  10*409600*4 = 16,384,000
    float*  cr_part = arena;                           //  10*524288*4 = 20,971,520
    __bf16* ub      = (__bf16*)(ws +  98467840);       //     819,200  [128][3200]
    __bf16* yb      = (__bf16*)(ws +  99287040);       //     819,200  [128][3200]
    __bf16* Gt      = (__bf16*)(ws + 100106240);       //     819,200  [128][3200]
    float*  wv      = (float*) (ws + 100925440);       //      12,800
    float*  p2v     = (float*) (ws + 100938240);
    float*  cvec    = (float*) (ws + 100938752);
    float*  lpart   = (float*) (ws + 100939264);       //       8,192

    // prep: x->fp8 | W_share^T->fp8 x64 (both half-swapped per row bit 3)
    prep_kernel<<<PREP_X + PREP_WS, 256, 0, stream>>>(xs, xq, W_share, Xf8, Wsf8);

    // z_share = relu((x @ W_share)*1/64 + b_share) [4416][3200] bf16, fp8 inputs;
    // + fused W_fine dual-layout conversion blocks (overlapped in-dispatch)
    {
        const int grid_g = (D_FEAT / 128) * (M_PAD / 128);   // 875
        gemm_fp8<<<grid_g + PREP_WF, 256, 0, stream>>>(
            Xf8, Wsf8, b_share, Zsb, W_fine, Wfb, WfTb,
            D_FEAT, D_IN, D_IN / 128, M_ROWS, D_FEAT / 128, M_PAD / 128);
    }

    // u = support means (bf16, padded to 128 rows) + channel pools
    ut_kernel<<<128, 256, 0, stream>>>(Zsb, ub, upool);
    att2_kernel<<<1, C_CH, 0, stream>>>(upool, W_att, b_att, wv);

    // zp_part[ks][p][j] = partial u @ Wf   (A=u, Bt=WfTb)  M=64, N=3200, K=3200
    gemm_bf16<<<25 * NKS, 256, 0, stream>>>(
        ub, WfTb, nullptr, nullptr, zp_part,
        D_FEAT, D_FEAT, 5, N_CLASS, 0, ZP_SLICE, 25, 1);

    // y = w*(zp+b_fine), p2, c   (sums the NKS zp partials)
    y_kernel<<<128, 256, 0, stream>>>(zp_part, wv, b_fine, yb, p2v, cvec);

    // gt_part[ks][p][k] = partial y @ Wf^T  (A=yb, Bt=Wfb natural)  M=128, N=3200
    gemm_bf16<<<25 * NKS, 256, 0, stream>>>(
        yb, Wfb, nullptr, nullptr, gt_part,
        D_FEAT, D_FEAT, 5, 128, 0, GT_SLICE, 25, 1);

    // Gt bf16 = sum of slices
    gtsum_kernel<<<(GT_SLICE / 4 + 255) / 256, 256, 0, stream>>>(gt_part, Gt);

    // cr_part[ks][i][p] = partial zs_q @ Gt^T   [4096][128]
    gemm_bf16<<<32 * NKS, 256, 0, stream>>>(
        Zsb + (size_t)NS * D_FEAT, Gt, nullptr, nullptr, cr_part,
        128, D_FEAT, 5, NQ, 0, CR_SLICE, 1, 32);

    // per-query log-softmax + loss/acc -> block partials (no atomics)
    loss_kernel<<<LOSS_BLKS, 256, 0, stream>>>(cr_part, p2v, cvec, lpart);

    writeout_kernel<<<1, 256, 0, stream>>>(lpart, out);
}

// Round 11
// 254.113 us; speedup vs baseline: 1.1251x; 1.1251x over previous
//
#include <hip/hip_runtime.h>
#include <math.h>

// Problem constants
#define N_CLASS 64
#define N_SUPPORT 5
#define N_QUERY 64
#define D_IN 1024
#define C_CH 128
#define WIN 5
#define D_FEAT 3200            // C*WIN*WIN
#define NS 320                 // N_CLASS*N_SUPPORT
#define NQ 4096                // N_CLASS*N_QUERY
#define M_ROWS 4416            // NS+NQ
#define M_PAD 4480             // 35 * 128

#define ZP_SLICE  (N_CLASS * D_FEAT)          // 204800
#define GT_SLICE  (128 * D_FEAT)              // 409600
#define CR_SLICE  (NQ * 128)                  // 524288
#define NKS       10                          // split-K slices
#define LOSS_BLKS (NQ / 4)                    // 1024

// prep kernel block-range partition (x + W_share only; Wf fused into ut dispatch)
#define PREP_X   4480                          // x->fp8 blocks
#define PREP_WS  3200                          // 100 x 32 (32x32 tiles)
#define CONV_WF  10000                         // Wf conversion blocks (in ut dispatch)

#define WS_SCALE    64.0f                      // W_share fp8 pre-scale (avoids denormals)
#define WS_INVSCALE 0.015625f

typedef __bf16 bf16x8 __attribute__((ext_vector_type(8)));
typedef __bf16 bf16x4 __attribute__((ext_vector_type(4)));
typedef float floatx4 __attribute__((ext_vector_type(4)));
typedef __attribute__((address_space(1))) const void* gptr_t;
typedef __attribute__((address_space(3))) void* lptr_t;

__device__ __forceinline__ float waveReduceSum(float v) {
    for (int off = 32; off > 0; off >>= 1) v += __shfl_xor(v, off, 64);
    return v;
}

// ------ prep: x->fp8 | W_share^T->fp8(x64); rows with (row>>3)&1 get their 8B
// ------ halves swapped inside each 16B unit (conflict-free fp8 LDS reads later)
__global__ __launch_bounds__(256) void prep_kernel(const float* __restrict__ xs,
                                                   const float* __restrict__ xq,
                                                   const float* __restrict__ W_share,
                                                   unsigned char* __restrict__ Xf8,
                                                   unsigned char* __restrict__ Wsf8)
{
    __shared__ float tile[32][33];
    const int b = blockIdx.x;
    const int t = threadIdx.x;

    if (b < PREP_X) {
        // x (xs|xq|zero-pad) -> fp8 e4m3 [M_PAD][1024], 4 elems per thread
        const int e = (b * 256 + t) * 4;
        const int row = e >> 10;
        const int col = e & 1023;
        float4 v = make_float4(0.f, 0.f, 0.f, 0.f);
        if (row < NS)          v = *(const float4*)(xs + (size_t)row * D_IN + col);
        else if (row < M_ROWS) v = *(const float4*)(xq + (size_t)(row - NS) * D_IN + col);
        int p = __builtin_amdgcn_cvt_pk_fp8_f32(v.x, v.y, 0, false);
        p     = __builtin_amdgcn_cvt_pk_fp8_f32(v.z, v.w, p, true);
        const int ocol = col ^ (((row >> 3) & 1) << 3);     // half-swap
        *(int*)(Xf8 + (size_t)row * D_IN + ocol) = p;
        return;
    }
    // W_share [1024][3200] -> Wsf8 [3200][1024] fp8, scaled x64, half-swapped
    const int tx = t & 31;
    const int ty = t >> 5;
    const int tb = b - PREP_X;
    const int n0 = (tb % 100) * 32;
    const int k0 = (tb / 100) * 32;
#pragma unroll
    for (int i = ty; i < 32; i += 8)
        tile[i][tx] = W_share[(size_t)(k0 + i) * D_FEAT + n0 + tx];
    __syncthreads();
#pragma unroll
    for (int i = ty; i < 32; i += 8) {
        const int p = __builtin_amdgcn_cvt_pk_fp8_f32(tile[tx][i] * WS_SCALE, 0.f,
                                                      0, false);
        const int n = n0 + i;
        const int k = (k0 + tx) ^ (((n >> 3) & 1) << 3);    // half-swap
        Wsf8[(size_t)n * D_IN + k] = (unsigned char)(p & 0xff);
    }
}

// -------- fp8 MFMA GEMM (gemm1): out_bf16 = relu(A @ Bt^T * 1/64 + bias) ----------
// 128x128 tile, BK=128, LDS rows 128 B. Store: 16B slot = c16 ^ (row&7). Read:
// unit = (qq>>1)^(r16&7), half = (qq&1)^((r16>>3)&1) [data pre-half-swapped in
// prep] -> each 16-lane phase covers all 32 banks exactly once: conflict-free
// (verified R10: SQ_LDS_BANK_CONFLICT == 0).
__global__ __launch_bounds__(256) void gemm_fp8(const unsigned char* __restrict__ A,
                                                const unsigned char* __restrict__ Bt,
                                                const float* __restrict__ bias,
                                                __bf16* __restrict__ out_bf,
                                                int N, int strideK, int kIters,
                                                int Mout, int nbx, int nby)
{
    __shared__ __align__(16) char smem[32768];   // A tile @0 (16 KB) | B tile @16384

    int bx, by;
    {
        const int b  = blockIdx.x;
        const int fg = nbx >> 3;
        const int full = fg * 8 * nby;
        if (b < full) {
            const int g = b / (8 * nby);
            const int r = b - g * 8 * nby;
            bx = g * 8 + (r & 7);
            by = r >> 3;
        } else {
            const int rem = nbx - fg * 8;
            const int r = b - full;
            bx = fg * 8 + r % rem;
            by = r / rem;
        }
    }

    const int t    = threadIdx.x;
    const int lane = t & 63;
    const int w    = t >> 6;
    const int wm   = w >> 1;
    const int wn   = w & 1;
    const int bm   = by * 128;
    const int bn   = bx * 128;

    const int q    = lane >> 4;       // k-group within 32-k subtile
    const int r16  = lane & 15;
    const int b7   = r16 & 7;
    const int hs   = (r16 >> 3) & 1;  // half-select (matches prep's pre-swap)

    // staging line geometry (line i: rows i*32 + (t>>3), slot t&7)
    const int smRow  = t >> 3;                        // 0..31 (+ i*32)
    const int sgk16  = ((t & 7) ^ ((t >> 3) & 7)) * 16;  // global chunk byte offset

    floatx4 acc[4][4] = {};

    for (int ki = 0; ki < kIters; ++ki) {
        const int k0 = ki * 128;
        __syncthreads();
#pragma unroll
        for (int i = 0; i < 4; ++i) {
            const unsigned char* ga = A  + (size_t)(bm + i * 32 + smRow) * strideK
                                         + k0 + sgk16;
            const unsigned char* gb = Bt + (size_t)(bn + i * 32 + smRow) * strideK
                                         + k0 + sgk16;
            char* la = smem +         i * 4096 + t * 16;
            char* lb = smem + 16384 + i * 4096 + t * 16;
            __builtin_amdgcn_global_load_lds((gptr_t)ga, (lptr_t)la, 16, 0, 0);
            __builtin_amdgcn_global_load_lds((gptr_t)gb, (lptr_t)lb, 16, 0, 0);
        }
        __syncthreads();

#pragma unroll
        for (int s32 = 0; s32 < 4; ++s32) {
            const int qq = s32 * 4 + q;               // k-group 0..15
            const int colOff = (((qq >> 1) ^ b7) * 16) + (((qq & 1) ^ hs) * 8);
            long av[4], bv[4];
#pragma unroll
            for (int mi = 0; mi < 4; ++mi)
                av[mi] = *(const long*)(smem
                            + (wm * 64 + mi * 16 + r16) * 128 + colOff);
#pragma unroll
            for (int ni = 0; ni < 4; ++ni)
                bv[ni] = *(const long*)(smem + 16384
                            + (wn * 64 + ni * 16 + r16) * 128 + colOff);
#pragma unroll
            for (int mi = 0; mi < 4; ++mi)
#pragma unroll
                for (int ni = 0; ni < 4; ++ni)
                    acc[mi][ni] = __builtin_amdgcn_mfma_f32_16x16x32_fp8_fp8(
                        av[mi], bv[ni], acc[mi][ni], 0, 0, 0);
        }
    }

    // epilogue: C/D layout col=lane&15, row=(lane>>4)*4+reg; descale 1/64
#pragma unroll
    for (int ni = 0; ni < 4; ++ni) {
        const int col = bn + wn * 64 + ni * 16 + r16;
        const float bcol = bias[col];
#pragma unroll
        for (int mi = 0; mi < 4; ++mi) {
#pragma unroll
            for (int reg = 0; reg < 4; ++reg) {
                const int row = bm + wm * 64 + mi * 16 + q * 4 + reg;
                if (row < Mout) {
                    float v = acc[mi][ni][reg] * WS_INVSCALE + bcol;
                    v = fmaxf(v, 0.f);
                    out_bf[(size_t)row * N + col] = (__bf16)v;
                }
            }
        }
    }
}

// ---------------- bf16 MFMA GEMM: split-K partials or full ----------------
__global__ __launch_bounds__(256) void gemm_bf16(const __bf16* __restrict__ A,
                                                 const __bf16* __restrict__ Bt,
                                                 const float* __restrict__ bias,
                                                 __bf16* __restrict__ out_bf,
                                                 float* __restrict__ out_f32,
                                                 int N, int strideK, int kIters,
                                                 int Mout, int relu, int sliceStride,
                                                 int nbx, int nby)
{
    __shared__ __align__(16) char smem[32768];   // sA: s0@0 s1@8192 | sB: @16384,@24576

    int bx, by, ks;
    {
        const int nbxy = nbx * nby;
        ks = blockIdx.x / nbxy;
        const int b = blockIdx.x - ks * nbxy;
        const int fg = nbx >> 3;
        const int full = fg * 8 * nby;
        if (b < full) {
            const int g = b / (8 * nby);
            const int r = b - g * 8 * nby;
            bx = g * 8 + (r & 7);
            by = r >> 3;
        } else {
            const int rem = nbx - fg * 8;
            const int r = b - full;
            bx = fg * 8 + r % rem;
            by = r / rem;
        }
    }

    const int t    = threadIdx.x;
    const int lane = t & 63;
    const int w    = t >> 6;
    const int wm   = w >> 1;
    const int wn   = w & 1;
    const int bm   = by * 128;
    const int bn   = bx * 128;

    const int q    = lane >> 4;
    const int r16  = lane & 15;
    const int sw   = (r16 >> 1) & 3;
    const int cA   = (q ^ sw) * 8;

    const int srow   = w * 16 + (lane >> 2);
    const int sglob8 = (((lane & 3) ^ ((lane >> 3) & 3))) * 8;

    const int kBase = ks * kIters * 64;
    floatx4 acc[4][4] = {};

    for (int ki = 0; ki < kIters; ++ki) {
        const int k0 = kBase + ki * 64;
        __syncthreads();
#pragma unroll
        for (int s = 0; s < 2; ++s) {
#pragma unroll
            for (int j = 0; j < 2; ++j) {
                const __bf16* ga = A  + (size_t)(bm + j * 64 + srow) * strideK
                                      + k0 + s * 32 + sglob8;
                const __bf16* gb = Bt + (size_t)(bn + j * 64 + srow) * strideK
                                      + k0 + s * 32 + sglob8;
                char* la = smem +         s * 8192 + (j * 256 + w * 64) * 16;
                char* lb = smem + 16384 + s * 8192 + (j * 256 + w * 64) * 16;
                __builtin_amdgcn_global_load_lds((gptr_t)ga, (lptr_t)la, 16, 0, 0);
                __builtin_amdgcn_global_load_lds((gptr_t)gb, (lptr_t)lb, 16, 0, 0);
            }
        }
        __syncthreads();

#pragma unroll
        for (int s = 0; s < 2; ++s) {
            const __bf16* sAe = (const __bf16*)(smem +         s * 8192);
            const __bf16* sBe = (const __bf16*)(smem + 16384 + s * 8192);
            bf16x8 av[4], bv[4];
#pragma unroll
            for (int mi = 0; mi < 4; ++mi)
                av[mi] = *(const bf16x8*)(sAe + ((wm * 64 + mi * 16 + r16) * 32 + cA));
#pragma unroll
            for (int ni = 0; ni < 4; ++ni)
                bv[ni] = *(const bf16x8*)(sBe + ((wn * 64 + ni * 16 + r16) * 32 + cA));
#pragma unroll
            for (int mi = 0; mi < 4; ++mi)
#pragma unroll
                for (int ni = 0; ni < 4; ++ni)
                    acc[mi][ni] = __builtin_amdgcn_mfma_f32_16x16x32_bf16(
                        av[mi], bv[ni], acc[mi][ni], 0, 0, 0);
        }
    }

#pragma unroll
    for (int ni = 0; ni < 4; ++ni) {
        const int col = bn + wn * 64 + ni * 16 + r16;
        const float bcol = sliceStride ? 0.f : bias[col];
#pragma unroll
        for (int mi = 0; mi < 4; ++mi) {
#pragma unroll
            for (int reg = 0; reg < 4; ++reg) {
                const int row = bm + wm * 64 + mi * 16 + q * 4 + reg;
                if (row < Mout) {
                    if (sliceStride) {
                        out_f32[(size_t)ks * sliceStride + (size_t)row * N + col] =
                            acc[mi][ni][reg];
                    } else {
                        float v = acc[mi][ni][reg] + bcol;
                        if (relu) v = fmaxf(v, 0.f);
                        if (out_f32) out_f32[(size_t)row * N + col] = v;
                        else         out_bf [(size_t)row * N + col] = (__bf16)v;
                    }
                }
            }
        }
    }
}

// ---- fused dispatch: blocks 0..127 = support means + channel pools;
// ---- blocks 128.. = W_fine f32 -> Wfb natural + WfTb transposed (bf16).
// ---- ut (LDS-bound, ~10 us) hides under the BW-bound conversion (~25 us);
// ---- Wfb/WfTb not consumed until the zp GEMM two launches later.
__global__ __launch_bounds__(256) void ut_conv_kernel(const __bf16* __restrict__ z_share,
                                                      const float* __restrict__ W_fine,
                                                      __bf16* __restrict__ u,
                                                      float* __restrict__ upool,
                                                      __bf16* __restrict__ Wfb,
                                                      __bf16* __restrict__ WfTb)
{
    __shared__ __align__(16) char smem_u[D_FEAT * 4];   // 12.8 KB
    const int b = blockIdx.x;
    const int t = threadIdx.x;

    if (b >= 128) {
        // W_fine dual-layout conversion block
        float (*tile)[33] = (float(*)[33])smem_u;
        const int tb = b - 128;
        const int tx = t & 31;
        const int ty = t >> 5;
        const int n0 = (tb % 100) * 32;
        const int k0 = (tb / 100) * 32;
#pragma unroll
        for (int i = ty; i < 32; i += 8) {
            const float v = W_fine[(size_t)(k0 + i) * D_FEAT + n0 + tx];
            Wfb[(size_t)(k0 + i) * D_FEAT + n0 + tx] = (__bf16)v;
            tile[i][tx] = v;
        }
        __syncthreads();
#pragma unroll
        for (int i = ty; i < 32; i += 8)
            WfTb[(size_t)(n0 + i) * D_FEAT + k0 + tx] = (__bf16)tile[tx][i];
        return;
    }

    float* srow_ = (float*)smem_u;
    const int p = b;                 // 0..127
    if (p >= N_CLASS) {
        for (int k = t; k < D_FEAT; k += 256) u[(size_t)p * D_FEAT + k] = (__bf16)0.f;
        return;
    }
    const __bf16* base = z_share + (size_t)(p * N_SUPPORT) * D_FEAT;
    for (int k = t; k < D_FEAT; k += 256) {
        float s = 0.f;
#pragma unroll
        for (int ss = 0; ss < N_SUPPORT; ++ss) s += (float)base[(size_t)ss * D_FEAT + k];
        s *= (1.0f / N_SUPPORT);
        u[(size_t)p * D_FEAT + k] = (__bf16)s;
        srow_[k] = s;
    }
    __syncthreads();
    if (t < C_CH) {
        float pool = 0.f;
#pragma unroll
        for (int win = 0; win < 25; ++win) pool += srow_[t * 25 + win];
        upool[(size_t)p * C_CH + t] = pool;
    }
}

// ------------- att: pooled mean (from upool) -> matvec -> softmax -> w[3200] --------
__global__ __launch_bounds__(128) void att2_kernel(const float* __restrict__ upool,
                                                   const float* __restrict__ W_att,
                                                   const float* __restrict__ b_att,
                                                   float* __restrict__ wvec)
{
    __shared__ float s_pm[C_CH];
    __shared__ float s_att[C_CH];
    __shared__ float s_diag[C_CH];
    const int c = threadIdx.x;
    float a = 0.f;
    for (int p = 0; p < N_CLASS; ++p) a += upool[(size_t)p * C_CH + c];
    s_pm[c] = a * (1.0f / (N_CLASS * 25));
    __syncthreads();
    float acc = b_att[c];
    for (int k = 0; k < C_CH; ++k) acc += s_pm[k] * W_att[k * C_CH + c];
    s_att[c] = acc;
    __syncthreads();
    float m = -INFINITY;
    for (int k = 0; k < C_CH; ++k) m = fmaxf(m, s_att[k]);
    float s = 0.f;
    for (int k = 0; k < C_CH; ++k) s += expf(s_att[k] - m);
    s_diag[c] = expf(acc - m) / s * (float)C_CH;
    __syncthreads();
    for (int j = c; j < D_FEAT; j += C_CH) wvec[j] = s_diag[j / 25];
}

// ---------------- y = w*(sum zp_part + bf) bf16 [128 pad][3200]; p2; c --------------
__global__ __launch_bounds__(256) void y_kernel(const float* __restrict__ zp_part,
                                                const float* __restrict__ wv,
                                                const float* __restrict__ bf,
                                                __bf16* __restrict__ y,
                                                float* __restrict__ p2,
                                                float* __restrict__ cvec)
{
    __shared__ float s_red2[8];
    const int p = blockIdx.x;        // 0..127
    const int t = threadIdx.x;
    if (p >= N_CLASS) {
        for (int j = t; j < D_FEAT; j += 256) y[(size_t)p * D_FEAT + j] = (__bf16)0.f;
        return;
    }
    float s2 = 0.f, sc = 0.f;
    for (int j = t; j < D_FEAT; j += 256) {
        float zpf = bf[j];
#pragma unroll
        for (int ss = 0; ss < NKS; ++ss)
            zpf += zp_part[(size_t)ss * ZP_SLICE + (size_t)p * D_FEAT + j];
        const float wj = wv[j];
        y[(size_t)p * D_FEAT + j] = (__bf16)(wj * zpf);
        s2 += wj * zpf * zpf;
        sc += bf[j] * wj * zpf;
    }
    s2 = waveReduceSum(s2);
    sc = waveReduceSum(sc);
    const int lane = t & 63, wid = t >> 6;
    if (lane == 0) { s_red2[wid] = s2; s_red2[4 + wid] = sc; }
    __syncthreads();
    if (t == 0) {
        p2[p]   = s_red2[0] + s_red2[1] + s_red2[2] + s_red2[3];
        cvec[p] = s_red2[4] + s_red2[5] + s_red2[6] + s_red2[7];
    }
}

// ---------------- Gt[p][k] bf16 = sum of NKS fp32 slices [128][3200] ----------------
__global__ __launch_bounds__(256) void gtsum_kernel(const float* __restrict__ gp,
                                                    __bf16* __restrict__ Gt)
{
    const int i4 = blockIdx.x * 256 + threadIdx.x;     // over 409600/4
    if (i4 >= GT_SLICE / 4) return;
    float4 s = make_float4(0.f, 0.f, 0.f, 0.f);
#pragma unroll
    for (int ss = 0; ss < NKS; ++ss) {
        const float4 v = *(const float4*)(gp + (size_t)ss * GT_SLICE + i4 * 4);
        s.x += v.x; s.y += v.y; s.z += v.z; s.w += v.w;
    }
    bf16x4 o = { (__bf16)s.x, (__bf16)s.y, (__bf16)s.z, (__bf16)s.w };
    *(bf16x4*)(Gt + (size_t)i4 * 4) = o;
}

// ---------------- softmax/loss: one wave per query, block partials (no atomics) -----
__global__ __launch_bounds__(256) void loss_kernel(const float* __restrict__ cross_part,
                                                   const float* __restrict__ p2,
                                                   const float* __restrict__ cvec,
                                                   float* __restrict__ lpart)
{
    __shared__ float s_l[4], s_a[4];
    const int t = threadIdx.x;
    const int lane = t & 63, wid = t >> 6;
    const int i = blockIdx.x * 4 + wid;       // query 0..4095
    float cr = 0.f;
#pragma unroll
    for (int ss = 0; ss < NKS; ++ss)
        cr += cross_part[(size_t)ss * CR_SLICE + (size_t)i * 128 + lane];
    const float neg = 2.0f * (cr + cvec[lane]) - p2[lane];   // -(dist) + const/row
    float m = neg;
    for (int off = 32; off > 0; off >>= 1) m = fmaxf(m, __shfl_xor(m, off, 64));
    float e = expf(neg - m);
    float ssum = e;
    for (int off = 32; off > 0; off >>= 1) ssum += __shfl_xor(ssum, off, 64);
    const float lse = m + logf(ssum);
    const int tcls = i >> 6;
    const float negt = __shfl(neg, tcls, 64);
    float v = -neg; int bi = lane;            // argmin dist == argmax neg, first on tie
    for (int off = 32; off > 0; off >>= 1) {
        const float ov = __shfl_xor(v, off, 64);
        const int   oi = __shfl_xor(bi, off, 64);
        if (ov < v || (ov == v && oi < bi)) { v = ov; bi = oi; }
    }
    if (lane == 0) { s_l[wid] = lse - negt; s_a[wid] = (bi == tcls) ? 1.0f : 0.0f; }
    __syncthreads();
    if (t == 0) {
        lpart[blockIdx.x]             = s_l[0] + s_l[1] + s_l[2] + s_l[3];
        lpart[LOSS_BLKS + blockIdx.x] = s_a[0] + s_a[1] + s_a[2] + s_a[3];
    }
}

__global__ __launch_bounds__(256) void writeout_kernel(const float* __restrict__ lpart,
                                                       float* __restrict__ out)
{
    __shared__ float s_red2[8];
    const int t = threadIdx.x;
    float l = 0.f, a = 0.f;
    for (int k = t; k < LOSS_BLKS; k += 256) {
        l += lpart[k];
        a += lpart[LOSS_BLKS + k];
    }
    l = waveReduceSum(l);
    a = waveReduceSum(a);
    const int lane = t & 63, wid = t >> 6;
    if (lane == 0) { s_red2[wid] = l; s_red2[4 + wid] = a; }
    __syncthreads();
    if (t == 0) {
        out[0] = (s_red2[0] + s_red2[1] + s_red2[2] + s_red2[3]) * (1.0f / NQ);
        out[1] = (s_red2[4] + s_red2[5] + s_red2[6] + s_red2[7]) * (1.0f / NQ);
    }
}

extern "C" void kernel_launch(void* const* d_in, const int* in_sizes, int n_in,
                              void* d_out, int out_size, void* d_ws, size_t ws_size,
                              hipStream_t stream)
{
    const float* xs      = (const float*)d_in[0];
    const float* xq      = (const float*)d_in[1];
    const float* W_share = (const float*)d_in[2];
    const float* b_share = (const float*)d_in[3];
    const float* W_att   = (const float*)d_in[4];
    const float* b_att   = (const float*)d_in[5];
    const float* W_fine  = (const float*)d_in[6];
    const float* b_fine  = (const float*)d_in[7];
    float* out = (float*)d_out;

    // workspace layout (bytes); arena holds upool -> zp_part -> gt_part -> cr_part
    char* ws = (char*)d_ws;
    unsigned char* Xf8  = (unsigned char*)(ws);        //   4,587,520 [M_PAD][1024] fp8
    unsigned char* Wsf8 = (unsigned char*)(ws + 4587520); // 3,276,800 [3200][1024] fp8
    __bf16* Zsb     = (__bf16*)(ws +   7864320);       //  28,672,000
    __bf16* Wfb     = (__bf16*)(ws +  36536320);       //  20,480,000 natural [k][j]
    __bf16* WfTb    = (__bf16*)(ws +  57016320);       //  20,480,000 transposed [j][k]
    float*  arena   = (float*) (ws +  77496320);       //  20,971,520
    float*  upool   = arena;                           //  64*128*4 (dead before zp)
    float*  zp_part = arena;                           //  10*204800*4 =  8,192,000
    float*  gt_part = arena;                           //  10*409600*4 = 16,384,000
    float*  cr_part = arena;                           //  10*524288*4 = 20,971,520
    __bf16* ub      = (__bf16*)(ws +  98467840);       //     819,200  [128][3200]
    __bf16* yb      = (__bf16*)(ws +  99287040);       //     819,200  [128][3200]
    __bf16* Gt      = (__bf16*)(ws + 100106240);       //     819,200  [128][3200]
    float*  wv      = (float*) (ws + 100925440);       //      12,800
    float*  p2v     = (float*) (ws + 100938240);
    float*  cvec    = (float*) (ws + 100938752);
    float*  lpart   = (float*) (ws + 100939264);       //       8,192

    // prep: x->fp8 | W_share^T->fp8 x64 (both half-swapped per row bit 3)
    prep_kernel<<<PREP_X + PREP_WS, 256, 0, stream>>>(xs, xq, W_share, Xf8, Wsf8);

    // z_share = relu((x @ W_share)*1/64 + b_share) [4416][3200] bf16, fp8 inputs
    gemm_fp8<<<(D_FEAT / 128) * (M_PAD / 128), 256, 0, stream>>>(
        Xf8, Wsf8, b_share, Zsb,
        D_FEAT, D_IN, D_IN / 128, M_ROWS, D_FEAT / 128, M_PAD / 128);

    // support means + channel pools, fused with W_fine dual-layout conversion
    ut_conv_kernel<<<128 + CONV_WF, 256, 0, stream>>>(Zsb, W_fine, ub, upool,
                                                      Wfb, WfTb);
    att2_kernel<<<1, C_CH, 0, stream>>>(upool, W_att, b_att, wv);

    // zp_part[ks][p][j] = partial u @ Wf   (A=u, Bt=WfTb)  M=64, N=3200, K=3200
    gemm_bf16<<<25 * NKS, 256, 0, stream>>>(
        ub, WfTb, nullptr, nullptr, zp_part,
        D_FEAT, D_FEAT, 5, N_CLASS, 0, ZP_SLICE, 25, 1);

    // y = w*(zp+b_fine), p2, c   (sums the NKS zp partials)
    y_kernel<<<128, 256, 0, stream>>>(zp_part, wv, b_fine, yb, p2v, cvec);

    // gt_part[ks][p][k] = partial y @ Wf^T  (A=yb, Bt=Wfb natural)  M=128, N=3200
    gemm_bf16<<<25 * NKS, 256, 0, stream>>>(
        yb, Wfb, nullptr, nullptr, gt_part,
        D_FEAT, D_FEAT, 5, 128, 0, GT_SLICE, 25, 1);

    // Gt bf16 = sum of slices
    gtsum_kernel<<<(GT_SLICE / 4 + 255) / 256, 256, 0, stream>>>(gt_part, Gt);

    // cr_part[ks][i][p] = partial zs_q @ Gt^T   [4096][128]
    gemm_bf16<<<32 * NKS, 256, 0, stream>>>(
        Zsb + (size_t)NS * D_FEAT, Gt, nullptr, nullptr, cr_part,
        128, D_FEAT, 5, NQ, 0, CR_SLICE, 1, 32);

    // per-query log-softmax + loss/acc -> block partials (no atomics)
    loss_kernel<<<LOSS_BLKS, 256, 0, stream>>>(cr_part, p2v, cvec, lpart);

    writeout_kernel<<<1, 256, 0, stream>>>(lpart, out);
}